// Round 7
// baseline (69.575 us; speedup 1.0000x reference)
//
#include <hip/hip_runtime.h>
#include <hip/hip_bf16.h>
#include <cstdint>

#define Cc 64
#define Hh 128
#define Ww 128
#define OCn 128
#define HBLK 4
#define WT 64
#define WLs 72
#define HP 130
#define WP 136
#define NT 18
#define SLOT_SHORTS (WLs * Cc)  // 4608 shorts = 9216 B per row slot
#define XP_BYTES (((size_t)16 * HP * WP * Cc) * 2)  // 36,208,640
#define PRE_BLOCKS (16 * HP)                        // 2080, divisible by 8

typedef float f32x4 __attribute__((ext_vector_type(4)));
typedef __bf16 bf16x8 __attribute__((ext_vector_type(8)));
typedef short s16x8 __attribute__((ext_vector_type(8)));

union bs8 { s16x8 s; bf16x8 b; };
__device__ __forceinline__ bf16x8 as_bf16x8(s16x8 s) { bs8 u; u.s = s; return u.b; }

// ---------------- fused pre-pass + weight pack ----------------
// xp[b][hp][wp][c], hp = h+1 in [0,130), wp = w+1 in [0,136); zeros at borders.
// XCD-aligned: work u = (bid>>3) + (bid&7)*260  ->  XCD k owns b in {2k, 2k+1}.
// Blocks [PRE_BLOCKS, PRE_BLOCKS+36) pack the ternary weight into fragments:
// wpf[(t*8 + mb)*64 + lane], k-step order t = ((kh*3+kw)*2 + chalf).
__global__ __launch_bounds__(256) void prepass_kernel(const float* __restrict__ x,
                                                      const float* __restrict__ w,
                                                      unsigned short* __restrict__ xp,
                                                      s16x8* __restrict__ wpf) {
  int bid = blockIdx.x;
  int t = threadIdx.x;
  if (bid >= PRE_BLOCKS) {
    int idx = (bid - PRE_BLOCKS) * 256 + t;  // < 9216
    int l = idx & 63;
    int mb = (idx >> 6) & 7;
    int tt = idx >> 9;
    int ch = tt & 1;
    int o = tt >> 1;
    int kh = o / 3, kw = o % 3;
    int oc = mb * 16 + (l & 15);
    int kl0 = (l >> 4) * 8;
    bf16x8 v;
#pragma unroll
    for (int j = 0; j < 8; ++j) {
      int c = ch * 32 + kl0 + j;
      int ko = (c * 3 + kh) * 3 + kw;
      v[j] = (__bf16)w[ko * OCn + oc];
    }
    bs8 u; u.b = v;
    wpf[idx] = u.s;
    return;
  }
  int u = (bid >> 3) + (bid & 7) * 260;  // bijective: 2080 = 8 * 260
  int b = u / 130, hp = u - b * 130;
  size_t obase = ((size_t)b * HP + hp) * WP * Cc;
  s16x8 z = (s16x8){0, 0, 0, 0, 0, 0, 0, 0};
  if (hp == 0 || hp == HP - 1) {
    for (int ck = t; ck < WP * Cc / 8; ck += 256)
      *(s16x8*)(xp + obase + (size_t)ck * 8) = z;
    return;
  }
  int h = hp - 1;
  __shared__ float tile[Cc][Ww + 1];
  int wpx = t & 127, chalf = t >> 7;
#pragma unroll
  for (int k = 0; k < 32; ++k) {
    int c = chalf * 32 + k;
    tile[c][wpx] = __builtin_nontemporal_load(
        &x[(((size_t)b * Cc + c) * Hh + h) * Ww + wpx]);
  }
  __syncthreads();
#pragma unroll
  for (int k = 0; k < 4; ++k) {
    int idx = k * 256 + t;  // [0,1024): ww = idx>>3, cg = idx&7
    int ww = idx >> 3, cg = idx & 7;
    bf16x8 v;
#pragma unroll
    for (int j = 0; j < 8; ++j) v[j] = (__bf16)tile[cg * 8 + j][ww];
    bs8 uu; uu.b = v;
    *(s16x8*)(xp + obase + (size_t)(ww + 1) * Cc + cg * 8) = uu.s;
  }
  if (t < 16) {
    int wz = (t >> 3) ? (Ww + 1) : 0;  // wp = 0 or 129
    *(s16x8*)(xp + obase + (size_t)wz * Cc + (t & 7) * 8) = z;
  }
}

// ---------------- conv main kernel ----------------
// Operand-swapped MFMA: D = x_frag * w_frag  =>  D col = oc, row = px.
// A(x) and B(w) per-lane fragment layouts are identical for 16x16x32, so the
// fragments are unchanged from the previous round; only call order + stores.
__global__ __launch_bounds__(256) void conv_mfma_kernel(
    const unsigned short* __restrict__ xp, const s16x8* __restrict__ wpf,
    float* __restrict__ out) {
  __shared__ __align__(16) short xt[4 * SLOT_SHORTS];
  int tid = threadIdx.x;
  int bid = blockIdx.x;
  int wk = (bid >> 3) + (bid & 7) * 128;  // bijective: 1024 = 8 * 128; XCD k -> b in {2k,2k+1}
  int wt = wk & 1;
  int hb = (wk >> 1) & 31;
  int b = wk >> 6;
  int h0 = hb * HBLK;
  int wv = tid >> 6, lane = tid & 63;
  int l15 = lane & 15, l4 = lane >> 4;

  // async stage of image row h_img into slot (h_img+1)&3; linear LDS dest,
  // inverse-XOR-swizzled global source (chunk cg^(wl&7)), swizzle again on read.
  auto stage = [&](int h_img) {
    int slot = (h_img + 1) & 3;
    size_t rbase = (((size_t)b * HP + (h_img + 1)) * WP + wt * WT) * Cc;
    int cg = lane & 7, wo = lane >> 3;
    const unsigned short* src0 = xp + rbase + (size_t)wo * Cc + ((cg ^ wo) << 3);
    for (int i = wv; i < 9; i += 4) {
      const unsigned short* src = src0 + (size_t)i * 8 * Cc;
      short* dst = &xt[slot * SLOT_SHORTS + i * 512];
      __builtin_amdgcn_global_load_lds(
          (const __attribute__((address_space(1))) void*)src,
          (__attribute__((address_space(3))) void*)dst, 16, 0, 0);
    }
  };

  stage(h0 - 1);
  stage(h0);
  stage(h0 + 1);

  for (int i = 0; i < HBLK; ++i) {
    int h = h0 + i;
    __syncthreads();            // staged rows visible; prior readers done
    if (i < HBLK - 1) stage(h + 2);  // issue async prefetch before compute

    f32x4 acc[2][4];
#pragma unroll
    for (int mi = 0; mi < 2; ++mi)
#pragma unroll
      for (int ni = 0; ni < 4; ++ni)
        acc[mi][ni] = (f32x4){0.f, 0.f, 0.f, 0.f};

#pragma unroll
    for (int t = 0; t < NT; ++t) {
      int kh = t / 6, kw = (t >> 1) % 3, ch = t & 1;
      bf16x8 a0 = as_bf16x8(wpf[(t * 8 + wv * 2 + 0) * 64 + lane]);
      bf16x8 a1 = as_bf16x8(wpf[(t * 8 + wv * 2 + 1) * 64 + lane]);
      int slot = (h + kh) & 3;
      int cgr = ch * 4 + l4;  // reader's channel-chunk index
#pragma unroll
      for (int ni = 0; ni < 4; ++ni) {
        int wl2 = ni * 16 + l15 + kw;
        int caddr = slot * SLOT_SHORTS + wl2 * Cc + ((cgr ^ (wl2 & 7)) << 3);
        bf16x8 bfr = as_bf16x8(*(const s16x8*)&xt[caddr]);
        // swapped: x as A, w as B -> D col = oc, row = px
        acc[0][ni] = __builtin_amdgcn_mfma_f32_16x16x32_bf16(bfr, a0, acc[0][ni], 0, 0, 0);
        acc[1][ni] = __builtin_amdgcn_mfma_f32_16x16x32_bf16(bfr, a1, acc[1][ni], 0, 0, 0);
      }
    }

    // D mapping (swapped): col(oc)=lane&15, row(px)=(lane>>4)*4 + r
    // => each lane's 4 acc values are 4 consecutive pixels -> one f32x4 store.
#pragma unroll
    for (int mi = 0; mi < 2; ++mi)
#pragma unroll
      for (int ni = 0; ni < 4; ++ni) {
        int oc = wv * 32 + mi * 16 + l15;
        int w_img = wt * WT + ni * 16 + l4 * 4;
        float* po = out + (((size_t)(b * OCn + oc)) * Hh + h) * Ww + w_img;
        __builtin_nontemporal_store(acc[mi][ni], (f32x4*)po);
      }
  }
}

extern "C" void kernel_launch(void* const* d_in, const int* in_sizes, int n_in,
                              void* d_out, int out_size, void* d_ws, size_t ws_size,
                              hipStream_t stream) {
  const float* x = (const float*)d_in[0];
  const float* w = (const float*)d_in[1];
  float* out = (float*)d_out;
  unsigned short* xp = (unsigned short*)d_ws;
  s16x8* wpf = (s16x8*)((char*)d_ws + XP_BYTES);
  prepass_kernel<<<PRE_BLOCKS + 36, 256, 0, stream>>>(x, w, xp, wpf);
  conv_mfma_kernel<<<1024, 256, 0, stream>>>(xp, (const s16x8*)wpf, out);
}

// Round 8
// 65.867 us; speedup vs baseline: 1.0563x; 1.0563x over previous
//
#include <hip/hip_runtime.h>
#include <hip/hip_bf16.h>
#include <cstdint>

#define Cc 64
#define Hh 128
#define Ww 128
#define OCn 128
#define HBLK 4
#define WPS 136
#define HP 130
#define WP 136
#define NT 18
#define SLOT_SHORTS (WPS * Cc)  // 8704 shorts = 17408 B per row slot
#define XP_BYTES (((size_t)16 * HP * WP * Cc) * 2)  // 36,208,640
#define PRE_BLOCKS (16 * HP)                        // 2080, divisible by 8

typedef float f32x4 __attribute__((ext_vector_type(4)));
typedef __bf16 bf16x8 __attribute__((ext_vector_type(8)));
typedef short s16x8 __attribute__((ext_vector_type(8)));

union bs8 { s16x8 s; bf16x8 b; };
__device__ __forceinline__ bf16x8 as_bf16x8(s16x8 s) { bs8 u; u.s = s; return u.b; }

// ---------------- fused pre-pass + weight pack ----------------
// xp[b][hp][wp][c], hp = h+1 in [0,130), wp = w+1 in [0,136); zeros at borders.
// XCD-aligned: work u = (bid>>3) + (bid&7)*260  ->  XCD k owns b in {2k, 2k+1}.
// Blocks [PRE_BLOCKS, PRE_BLOCKS+36) pack the ternary weight into fragments:
// wpf[(t*8 + mb)*64 + lane], k-step order t = ((kh*3+kw)*2 + chalf).
__global__ __launch_bounds__(256) void prepass_kernel(const float* __restrict__ x,
                                                      const float* __restrict__ w,
                                                      unsigned short* __restrict__ xp,
                                                      s16x8* __restrict__ wpf) {
  int bid = blockIdx.x;
  int t = threadIdx.x;
  if (bid >= PRE_BLOCKS) {
    int idx = (bid - PRE_BLOCKS) * 256 + t;  // < 9216
    int l = idx & 63;
    int mb = (idx >> 6) & 7;
    int tt = idx >> 9;
    int ch = tt & 1;
    int o = tt >> 1;
    int kh = o / 3, kw = o % 3;
    int oc = mb * 16 + (l & 15);
    int kl0 = (l >> 4) * 8;
    bf16x8 v;
#pragma unroll
    for (int j = 0; j < 8; ++j) {
      int c = ch * 32 + kl0 + j;
      int ko = (c * 3 + kh) * 3 + kw;
      v[j] = (__bf16)w[ko * OCn + oc];
    }
    bs8 u; u.b = v;
    wpf[idx] = u.s;
    return;
  }
  int u = (bid >> 3) + (bid & 7) * 260;  // bijective: 2080 = 8 * 260
  int b = u / 130, hp = u - b * 130;
  size_t obase = ((size_t)b * HP + hp) * WP * Cc;
  s16x8 z = (s16x8){0, 0, 0, 0, 0, 0, 0, 0};
  if (hp == 0 || hp == HP - 1) {
    for (int ck = t; ck < WP * Cc / 8; ck += 256)
      *(s16x8*)(xp + obase + (size_t)ck * 8) = z;
    return;
  }
  int h = hp - 1;
  __shared__ float tile[Cc][Ww + 1];
  // vectorized f32x4 loads: thread (t&31) covers 4 px, (t>>5)*8 covers 8 channels
  int w4 = (t & 31) * 4, c0 = (t >> 5) * 8;
#pragma unroll
  for (int k = 0; k < 8; ++k) {
    int c = c0 + k;
    f32x4 v = *(const f32x4*)&x[(((size_t)b * Cc + c) * Hh + h) * Ww + w4];
#pragma unroll
    for (int j = 0; j < 4; ++j) tile[c][w4 + j] = v[j];
  }
  __syncthreads();
#pragma unroll
  for (int k = 0; k < 4; ++k) {
    int idx = k * 256 + t;  // [0,1024): ww = idx>>3, cg = idx&7
    int ww = idx >> 3, cg = idx & 7;
    bf16x8 v;
#pragma unroll
    for (int j = 0; j < 8; ++j) v[j] = (__bf16)tile[cg * 8 + j][ww];
    bs8 uu; uu.b = v;
    *(s16x8*)(xp + obase + (size_t)(ww + 1) * Cc + cg * 8) = uu.s;
  }
  if (t < 16) {
    int wz = (t >> 3) ? (Ww + 1) : 0;  // wp = 0 or 129
    *(s16x8*)(xp + obase + (size_t)wz * Cc + (t & 7) * 8) = z;
  }
}

// ---------------- conv main kernel: full 128-px row per block ----------------
// 4 waves each own 32 oc (mb = 2wv, 2wv+1) x 128 px; all 36 A-fragments
// preloaded into registers (144 VGPR) — zero steady-state A traffic.
__global__ __launch_bounds__(256, 2) void conv_mfma_kernel(
    const unsigned short* __restrict__ xp, const s16x8* __restrict__ wpf,
    float* __restrict__ out) {
  __shared__ __align__(16) short xt[4 * SLOT_SHORTS];  // 69632 B
  int tid = threadIdx.x;
  int bid = blockIdx.x;
  int wk = (bid >> 3) + (bid & 7) * 64;  // bijective: 512 = 8 * 64
  int hb = wk & 31;
  int b = wk >> 5;
  int h0 = hb * HBLK;
  int wv = tid >> 6, lane = tid & 63;
  int l15 = lane & 15, l4 = lane >> 4;

  // Preload this wave's 36 A-fragments once.
  bf16x8 af[NT][2];
#pragma unroll
  for (int t = 0; t < NT; ++t)
#pragma unroll
    for (int mi = 0; mi < 2; ++mi)
      af[t][mi] = as_bf16x8(wpf[(t * 8 + wv * 2 + mi) * 64 + lane]);

  // async stage of image row h_img into slot (h_img+1)&3; linear LDS dest,
  // inverse-XOR-swizzled global source (chunk cg^(wp&7)), swizzle again on read.
  auto stage = [&](int h_img) {
    int slot = (h_img + 1) & 3;
    size_t rbase = ((size_t)b * HP + (h_img + 1)) * WP * Cc;
    int cg = lane & 7, wo = lane >> 3;
    const unsigned short* src0 = xp + rbase + (size_t)wo * Cc + ((cg ^ wo) << 3);
    for (int i = wv; i < 17; i += 4) {
      const unsigned short* src = src0 + (size_t)i * 8 * Cc;
      short* dst = &xt[slot * SLOT_SHORTS + i * 512];
      __builtin_amdgcn_global_load_lds(
          (const __attribute__((address_space(1))) void*)src,
          (__attribute__((address_space(3))) void*)dst, 16, 0, 0);
    }
  };

  stage(h0 - 1);
  stage(h0);
  stage(h0 + 1);

  for (int i = 0; i < HBLK; ++i) {
    int h = h0 + i;
    __syncthreads();            // staged rows visible; prior readers done
    if (i < HBLK - 1) stage(h + 2);  // issue async prefetch before compute

    f32x4 acc[2][8];
#pragma unroll
    for (int mi = 0; mi < 2; ++mi)
#pragma unroll
      for (int ni = 0; ni < 8; ++ni)
        acc[mi][ni] = (f32x4){0.f, 0.f, 0.f, 0.f};

#pragma unroll
    for (int t = 0; t < NT; ++t) {
      int kh = t / 6, kw = (t >> 1) % 3, ch = t & 1;
      int slot = (h + kh) & 3;
      int cgr = ch * 4 + l4;  // reader's channel-chunk index
#pragma unroll
      for (int ni = 0; ni < 8; ++ni) {
        int wl2 = ni * 16 + l15 + kw;
        int caddr = slot * SLOT_SHORTS + wl2 * Cc + ((cgr ^ (wl2 & 7)) << 3);
        bf16x8 bfr = as_bf16x8(*(const s16x8*)&xt[caddr]);
        acc[0][ni] = __builtin_amdgcn_mfma_f32_16x16x32_bf16(af[t][0], bfr, acc[0][ni], 0, 0, 0);
        acc[1][ni] = __builtin_amdgcn_mfma_f32_16x16x32_bf16(af[t][1], bfr, acc[1][ni], 0, 0, 0);
      }
    }

    // D mapping: col(px)=lane&15, row(oc)=(lane>>4)*4 + r
#pragma unroll
    for (int mi = 0; mi < 2; ++mi)
#pragma unroll
      for (int ni = 0; ni < 8; ++ni) {
        int oc = wv * 32 + mi * 16 + l4 * 4;
        int w_img = ni * 16 + l15;
        float* po = out + (((size_t)(b * OCn + oc)) * Hh + h) * Ww + w_img;
#pragma unroll
        for (int r = 0; r < 4; ++r)
          __builtin_nontemporal_store(acc[mi][ni][r], po + (size_t)r * Hh * Ww);
      }
  }
}

extern "C" void kernel_launch(void* const* d_in, const int* in_sizes, int n_in,
                              void* d_out, int out_size, void* d_ws, size_t ws_size,
                              hipStream_t stream) {
  const float* x = (const float*)d_in[0];
  const float* w = (const float*)d_in[1];
  float* out = (float*)d_out;
  unsigned short* xp = (unsigned short*)d_ws;
  s16x8* wpf = (s16x8*)((char*)d_ws + XP_BYTES);
  prepass_kernel<<<PRE_BLOCKS + 36, 256, 0, stream>>>(x, w, xp, wpf);
  conv_mfma_kernel<<<512, 256, 0, stream>>>(xp, (const s16x8*)wpf, out);
}

// Round 9
// 64.733 us; speedup vs baseline: 1.0748x; 1.0175x over previous
//
#include <hip/hip_runtime.h>
#include <hip/hip_bf16.h>
#include <cstdint>

#define Cc 64
#define Hh 128
#define Ww 128
#define OCn 128
#define HBLK 4
#define WT 64
#define WLs 66
#define HP 130
#define WP 136
#define NT 18
#define SLOT_SHORTS (WLs * Cc)  // 4224 shorts = 8448 B per row slot; 4 slots = 33792 B
#define XP_BYTES (((size_t)16 * HP * WP * Cc) * 2)  // 36,208,640
#define PRE_BLOCKS (16 * HP)                        // 2080, divisible by 8

typedef float f32x4 __attribute__((ext_vector_type(4)));
typedef __bf16 bf16x8 __attribute__((ext_vector_type(8)));
typedef short s16x8 __attribute__((ext_vector_type(8)));

union bs8 { s16x8 s; bf16x8 b; };
__device__ __forceinline__ bf16x8 as_bf16x8(s16x8 s) { bs8 u; u.s = s; return u.b; }

// ---------------- fused pre-pass + weight pack (R6-exact) ----------------
// xp[b][hp][wp][c], hp = h+1 in [0,130), wp = w+1 in [0,136); zeros at borders.
// XCD-aligned: work u = (bid>>3) + (bid&7)*260  ->  XCD k owns b in {2k, 2k+1}.
// Blocks [PRE_BLOCKS, PRE_BLOCKS+36) pack the ternary weight into fragments:
// wpf[(t*8 + mb)*64 + lane], k-step order t = ((kh*3+kw)*2 + chalf).
__global__ __launch_bounds__(256) void prepass_kernel(const float* __restrict__ x,
                                                      const float* __restrict__ w,
                                                      unsigned short* __restrict__ xp,
                                                      s16x8* __restrict__ wpf) {
  int bid = blockIdx.x;
  int t = threadIdx.x;
  if (bid >= PRE_BLOCKS) {
    int idx = (bid - PRE_BLOCKS) * 256 + t;  // < 9216
    int l = idx & 63;
    int mb = (idx >> 6) & 7;
    int tt = idx >> 9;
    int ch = tt & 1;
    int o = tt >> 1;
    int kh = o / 3, kw = o % 3;
    int oc = mb * 16 + (l & 15);
    int kl0 = (l >> 4) * 8;
    bf16x8 v;
#pragma unroll
    for (int j = 0; j < 8; ++j) {
      int c = ch * 32 + kl0 + j;
      int ko = (c * 3 + kh) * 3 + kw;
      v[j] = (__bf16)w[ko * OCn + oc];
    }
    bs8 u; u.b = v;
    wpf[idx] = u.s;
    return;
  }
  int u = (bid >> 3) + (bid & 7) * 260;  // bijective: 2080 = 8 * 260
  int b = u / 130, hp = u - b * 130;
  size_t obase = ((size_t)b * HP + hp) * WP * Cc;
  s16x8 z = (s16x8){0, 0, 0, 0, 0, 0, 0, 0};
  if (hp == 0 || hp == HP - 1) {
    for (int ck = t; ck < WP * Cc / 8; ck += 256)
      *(s16x8*)(xp + obase + (size_t)ck * 8) = z;
    return;
  }
  int h = hp - 1;
  __shared__ float tile[Cc][Ww + 1];
  int wpx = t & 127, chalf = t >> 7;
#pragma unroll
  for (int k = 0; k < 32; ++k) {
    int c = chalf * 32 + k;
    tile[c][wpx] = __builtin_nontemporal_load(
        &x[(((size_t)b * Cc + c) * Hh + h) * Ww + wpx]);
  }
  __syncthreads();
#pragma unroll
  for (int k = 0; k < 4; ++k) {
    int idx = k * 256 + t;  // [0,1024): ww = idx>>3, cg = idx&7
    int ww = idx >> 3, cg = idx & 7;
    bf16x8 v;
#pragma unroll
    for (int j = 0; j < 8; ++j) v[j] = (__bf16)tile[cg * 8 + j][ww];
    bs8 uu; uu.b = v;
    *(s16x8*)(xp + obase + (size_t)(ww + 1) * Cc + cg * 8) = uu.s;
  }
  if (t < 16) {
    int wz = (t >> 3) ? (Ww + 1) : 0;  // wp = 0 or 129
    *(s16x8*)(xp + obase + (size_t)wz * Cc + (t & 7) * 8) = z;
  }
}

// ---------------- conv main kernel (R6 structure, 4 blocks/CU target) ----------------
__global__ __launch_bounds__(256, 4) void conv_mfma_kernel(
    const unsigned short* __restrict__ xp, const s16x8* __restrict__ wpf,
    float* __restrict__ out) {
  __shared__ __align__(16) short xt[4 * SLOT_SHORTS];  // 33792 B
  int tid = threadIdx.x;
  int bid = blockIdx.x;
  int wk = (bid >> 3) + (bid & 7) * 128;  // bijective: 1024 = 8 * 128; XCD k -> b in {2k,2k+1}
  int wt = wk & 1;
  int hb = (wk >> 1) & 31;
  int b = wk >> 6;
  int h0 = hb * HBLK;
  int wv = tid >> 6, lane = tid & 63;
  int l15 = lane & 15, l4 = lane >> 4;

  // async stage of image row h_img into slot (h_img+1)&3; linear LDS dest,
  // inverse-XOR-swizzled global source (chunk cg^(px&7)), swizzle again on read.
  // 66 px per row (exact 64+2 halo): i=0..7 full-wave chunks, i=8 lanes<16 only.
  auto stage = [&](int h_img) {
    int slot = (h_img + 1) & 3;
    size_t rbase = (((size_t)b * HP + (h_img + 1)) * WP + wt * WT) * Cc;
    int cg = lane & 7, wo = lane >> 3;
    const unsigned short* src0 = xp + rbase + (size_t)wo * Cc + ((cg ^ wo) << 3);
    for (int i = wv; i < 9; i += 4) {
      if (i == 8 && lane >= 16) continue;
      const unsigned short* src = src0 + (size_t)i * 8 * Cc;
      short* dst = &xt[slot * SLOT_SHORTS + i * 512];
      __builtin_amdgcn_global_load_lds(
          (const __attribute__((address_space(1))) void*)src,
          (__attribute__((address_space(3))) void*)dst, 16, 0, 0);
    }
  };

  stage(h0 - 1);
  stage(h0);
  stage(h0 + 1);

  for (int i = 0; i < HBLK; ++i) {
    int h = h0 + i;
    __syncthreads();            // staged rows visible; prior readers done
    if (i < HBLK - 1) stage(h + 2);  // issue async prefetch before compute

    f32x4 acc[2][4];
#pragma unroll
    for (int mi = 0; mi < 2; ++mi)
#pragma unroll
      for (int ni = 0; ni < 4; ++ni)
        acc[mi][ni] = (f32x4){0.f, 0.f, 0.f, 0.f};

#pragma unroll 6
    for (int t = 0; t < NT; ++t) {
      int kh = t / 6, kw = (t >> 1) % 3, ch = t & 1;
      bf16x8 a0 = as_bf16x8(wpf[(t * 8 + wv * 2 + 0) * 64 + lane]);
      bf16x8 a1 = as_bf16x8(wpf[(t * 8 + wv * 2 + 1) * 64 + lane]);
      int slot = (h + kh) & 3;
      int cgr = ch * 4 + l4;  // reader's channel-chunk index
#pragma unroll
      for (int ni = 0; ni < 4; ++ni) {
        int wl2 = ni * 16 + l15 + kw;
        int caddr = slot * SLOT_SHORTS + wl2 * Cc + ((cgr ^ (wl2 & 7)) << 3);
        bf16x8 bfr = as_bf16x8(*(const s16x8*)&xt[caddr]);
        acc[0][ni] = __builtin_amdgcn_mfma_f32_16x16x32_bf16(a0, bfr, acc[0][ni], 0, 0, 0);
        acc[1][ni] = __builtin_amdgcn_mfma_f32_16x16x32_bf16(a1, bfr, acc[1][ni], 0, 0, 0);
      }
    }

    // D mapping: col(px)=lane&15, row(oc)=(lane>>4)*4 + r
#pragma unroll
    for (int mi = 0; mi < 2; ++mi)
#pragma unroll
      for (int ni = 0; ni < 4; ++ni) {
        int oc = wv * 32 + mi * 16 + l4 * 4;
        int w_img = wt * WT + ni * 16 + l15;
        float* po = out + (((size_t)(b * OCn + oc)) * Hh + h) * Ww + w_img;
#pragma unroll
        for (int r = 0; r < 4; ++r)
          __builtin_nontemporal_store(acc[mi][ni][r], po + (size_t)r * Hh * Ww);
      }
  }
}

extern "C" void kernel_launch(void* const* d_in, const int* in_sizes, int n_in,
                              void* d_out, int out_size, void* d_ws, size_t ws_size,
                              hipStream_t stream) {
  const float* x = (const float*)d_in[0];
  const float* w = (const float*)d_in[1];
  float* out = (float*)d_out;
  unsigned short* xp = (unsigned short*)d_ws;
  s16x8* wpf = (s16x8*)((char*)d_ws + XP_BYTES);
  prepass_kernel<<<PRE_BLOCKS + 36, 256, 0, stream>>>(x, w, xp, wpf);
  conv_mfma_kernel<<<1024, 256, 0, stream>>>(xp, (const s16x8*)wpf, out);
}

// Round 10
// 59.109 us; speedup vs baseline: 1.1771x; 1.0951x over previous
//
#include <hip/hip_runtime.h>
#include <hip/hip_bf16.h>
#include <cstdint>

#define Cc 64
#define Hh 128
#define Ww 128
#define OCn 128
#define HBLK 4
#define WT 64
#define WLs 72
#define HP 130
#define WP 136
#define NT 18
#define SLOT_SHORTS (WLs * Cc)  // 4608 shorts = 9216 B per row slot
#define XP_BYTES (((size_t)16 * HP * WP * Cc) * 2)  // 36,208,640
#define PRE_BLOCKS (16 * HP)                        // 2080, divisible by 8

typedef float f32x4 __attribute__((ext_vector_type(4)));
typedef __bf16 bf16x8 __attribute__((ext_vector_type(8)));
typedef short s16x8 __attribute__((ext_vector_type(8)));

union bs8 { s16x8 s; bf16x8 b; };
__device__ __forceinline__ bf16x8 as_bf16x8(s16x8 s) { bs8 u; u.s = s; return u.b; }

// ---------------- fused pre-pass + weight pack ----------------
// xp[b][hp][wp][c], hp = h+1 in [0,130), wp = w+1 in [0,136); zeros at borders.
// XCD-aligned: work u = (bid>>3) + (bid&7)*260  ->  XCD k owns b in {2k, 2k+1}.
// Blocks [PRE_BLOCKS, PRE_BLOCKS+36) pack the ternary weight into fragments:
// wpf[(t*8 + mb)*64 + lane], k-step order t = ((kh*3+kw)*2 + chalf).
__global__ __launch_bounds__(256) void prepass_kernel(const float* __restrict__ x,
                                                      const float* __restrict__ w,
                                                      unsigned short* __restrict__ xp,
                                                      s16x8* __restrict__ wpf) {
  int bid = blockIdx.x;
  int t = threadIdx.x;
  if (bid >= PRE_BLOCKS) {
    int idx = (bid - PRE_BLOCKS) * 256 + t;  // < 9216
    int l = idx & 63;
    int mb = (idx >> 6) & 7;
    int tt = idx >> 9;
    int ch = tt & 1;
    int o = tt >> 1;
    int kh = o / 3, kw = o % 3;
    int oc = mb * 16 + (l & 15);
    int kl0 = (l >> 4) * 8;
    bf16x8 v;
#pragma unroll
    for (int j = 0; j < 8; ++j) {
      int c = ch * 32 + kl0 + j;
      int ko = (c * 3 + kh) * 3 + kw;
      v[j] = (__bf16)w[ko * OCn + oc];
    }
    bs8 u; u.b = v;
    wpf[idx] = u.s;
    return;
  }
  int u = (bid >> 3) + (bid & 7) * 260;  // bijective: 2080 = 8 * 260
  int b = u / 130, hp = u - b * 130;
  size_t obase = ((size_t)b * HP + hp) * WP * Cc;
  s16x8 z = (s16x8){0, 0, 0, 0, 0, 0, 0, 0};
  if (hp == 0 || hp == HP - 1) {
    for (int ck = t; ck < WP * Cc / 8; ck += 256)
      *(s16x8*)(xp + obase + (size_t)ck * 8) = z;
    return;
  }
  int h = hp - 1;
  __shared__ float tile[Cc][Ww + 1];
  // G13: vectorized f32x4 loads — thread (t&31) covers 4 px, (t>>5)*8 covers 8 ch
  int w4 = (t & 31) * 4, c0 = (t >> 5) * 8;
#pragma unroll
  for (int k = 0; k < 8; ++k) {
    int c = c0 + k;
    f32x4 v = *(const f32x4*)&x[(((size_t)b * Cc + c) * Hh + h) * Ww + w4];
#pragma unroll
    for (int j = 0; j < 4; ++j) tile[c][w4 + j] = v[j];
  }
  __syncthreads();
#pragma unroll
  for (int k = 0; k < 4; ++k) {
    int idx = k * 256 + t;  // [0,1024): ww = idx>>3, cg = idx&7
    int ww = idx >> 3, cg = idx & 7;
    bf16x8 v;
#pragma unroll
    for (int j = 0; j < 8; ++j) v[j] = (__bf16)tile[cg * 8 + j][ww];
    bs8 uu; uu.b = v;
    *(s16x8*)(xp + obase + (size_t)(ww + 1) * Cc + cg * 8) = uu.s;
  }
  if (t < 16) {
    int wz = (t >> 3) ? (Ww + 1) : 0;  // wp = 0 or 129
    *(s16x8*)(xp + obase + (size_t)wz * Cc + (t & 7) * 8) = z;
  }
}

// ---------------- conv main kernel (R6-exact structure) ----------------
__global__ __launch_bounds__(256) void conv_mfma_kernel(
    const unsigned short* __restrict__ xp, const s16x8* __restrict__ wpf,
    float* __restrict__ out) {
  __shared__ __align__(16) short xt[4 * SLOT_SHORTS];
  int tid = threadIdx.x;
  int bid = blockIdx.x;
  int wk = (bid >> 3) + (bid & 7) * 128;  // bijective: 1024 = 8 * 128; XCD k -> b in {2k,2k+1}
  int wt = wk & 1;
  int hb = (wk >> 1) & 31;
  int b = wk >> 6;
  int h0 = hb * HBLK;
  int wv = tid >> 6, lane = tid & 63;
  int l15 = lane & 15, l4 = lane >> 4;

  // async stage of image row h_img into slot (h_img+1)&3; linear LDS dest,
  // inverse-XOR-swizzled global source (chunk cg^(wl&7)), swizzle again on read.
  auto stage = [&](int h_img) {
    int slot = (h_img + 1) & 3;
    size_t rbase = (((size_t)b * HP + (h_img + 1)) * WP + wt * WT) * Cc;
    int cg = lane & 7, wo = lane >> 3;
    const unsigned short* src0 = xp + rbase + (size_t)wo * Cc + ((cg ^ wo) << 3);
    for (int i = wv; i < 9; i += 4) {
      const unsigned short* src = src0 + (size_t)i * 8 * Cc;
      short* dst = &xt[slot * SLOT_SHORTS + i * 512];
      __builtin_amdgcn_global_load_lds(
          (const __attribute__((address_space(1))) void*)src,
          (__attribute__((address_space(3))) void*)dst, 16, 0, 0);
    }
  };

  stage(h0 - 1);
  stage(h0);
  stage(h0 + 1);

  for (int i = 0; i < HBLK; ++i) {
    int h = h0 + i;
    __syncthreads();            // staged rows visible; prior readers done
    if (i < HBLK - 1) stage(h + 2);  // issue async prefetch before compute

    f32x4 acc[2][4];
#pragma unroll
    for (int mi = 0; mi < 2; ++mi)
#pragma unroll
      for (int ni = 0; ni < 4; ++ni)
        acc[mi][ni] = (f32x4){0.f, 0.f, 0.f, 0.f};

#pragma unroll
    for (int t = 0; t < NT; ++t) {
      int kh = t / 6, kw = (t >> 1) % 3, ch = t & 1;
      bf16x8 a0 = as_bf16x8(wpf[(t * 8 + wv * 2 + 0) * 64 + lane]);
      bf16x8 a1 = as_bf16x8(wpf[(t * 8 + wv * 2 + 1) * 64 + lane]);
      int slot = (h + kh) & 3;
      int cgr = ch * 4 + l4;  // reader's channel-chunk index
#pragma unroll
      for (int ni = 0; ni < 4; ++ni) {
        int wl2 = ni * 16 + l15 + kw;
        int caddr = slot * SLOT_SHORTS + wl2 * Cc + ((cgr ^ (wl2 & 7)) << 3);
        bf16x8 bfr = as_bf16x8(*(const s16x8*)&xt[caddr]);
        acc[0][ni] = __builtin_amdgcn_mfma_f32_16x16x32_bf16(a0, bfr, acc[0][ni], 0, 0, 0);
        acc[1][ni] = __builtin_amdgcn_mfma_f32_16x16x32_bf16(a1, bfr, acc[1][ni], 0, 0, 0);
      }
    }

    // D mapping: col(px)=lane&15, row(oc)=(lane>>4)*4 + r
    // store order (mi, r, ni): consecutive stores walk px within the same
    // oc-row -> adjacent 64B halves of 128B lines for write combining.
#pragma unroll
    for (int mi = 0; mi < 2; ++mi)
#pragma unroll
      for (int r = 0; r < 4; ++r) {
        int oc = wv * 32 + mi * 16 + l4 * 4 + r;
        float* po = out + (((size_t)(b * OCn + oc)) * Hh + h) * Ww + wt * WT + l15;
#pragma unroll
        for (int ni = 0; ni < 4; ++ni)
          __builtin_nontemporal_store(acc[mi][ni][r], po + ni * 16);
      }
  }
}

extern "C" void kernel_launch(void* const* d_in, const int* in_sizes, int n_in,
                              void* d_out, int out_size, void* d_ws, size_t ws_size,
                              hipStream_t stream) {
  const float* x = (const float*)d_in[0];
  const float* w = (const float*)d_in[1];
  float* out = (float*)d_out;
  unsigned short* xp = (unsigned short*)d_ws;
  s16x8* wpf = (s16x8*)((char*)d_ws + XP_BYTES);
  prepass_kernel<<<PRE_BLOCKS + 36, 256, 0, stream>>>(x, w, xp, wpf);
  conv_mfma_kernel<<<1024, 256, 0, stream>>>(xp, (const s16x8*)wpf, out);
}